// Round 10
// baseline (161.536 us; speedup 1.0000x reference)
//
#include <hip/hip_runtime.h>
#include <stdint.h>

#define BATCH 16
#define HH 1024
#define WW 1024
#define TH 8                  // output rows per block
#define HALO 4
#define ROWS (TH + 2*HALO)    // 16 staged rows
#define WORDS (WW/64)         // 16 uint64 words per row
#define WPAD (WORDS + 1)      // padded inner dim: kills ds_read_b64 bank conflicts
#define NTHREADS 256
#define NWAVES (NTHREADS/64)
#define NBLOCKS_MSE (BATCH * (HH / TH))    // 2048
#define COUNT_WORDS (BATCH * HH * (WW/16)) // 1,048,576 uint64 = 8 MB

// spread 16 bits -> 16 nibbles (bit i -> bit 4i)
__device__ __forceinline__ unsigned long long spread16(unsigned int s) {
    unsigned long long x = s & 0xFFFFull;
    x = (x | (x << 24)) & 0x000000FF000000FFull;
    x = (x | (x << 12)) & 0x000F000F000F000Full;
    x = (x | (x << 6))  & 0x0303030303030303ull;
    x = (x | (x << 3))  & 0x1111111111111111ull;
    return x;
}

// ---------- kernel 1: tile pack + 4 erosions -> 4-bit count plane (8 MB) ----
// e4⊆e3⊆e2⊆e1⊆y, so count c=y+e1+e2+e3+e4 determines everything:
// y = (c>0), w = (c==0||c==5)?0.8:(0.3+0.1c).
__global__ __launch_bounds__(NTHREADS) void pack_erode_kernel(
    const float* __restrict__ y_true,
    unsigned long long* __restrict__ counts)
{
    __shared__ unsigned long long bits0[ROWS][WPAD];   // packed y_true (kept)
    __shared__ unsigned long long bufA[ROWS][WPAD];    // erosion ping
    __shared__ unsigned long long bufB[ROWS][WPAD];    // erosion pong
    __shared__ unsigned long long E[4][TH][WPAD];      // e1..e4 central bit-planes

    const int tid = threadIdx.x;
    const int im = blockIdx.x / (HH / TH);
    const int rb = blockIdx.x % (HH / TH);
    const int r0 = rb * TH - HALO;  // global row of staged row 0

    const float* yt = y_true + (size_t)im * HH * WW;

    // ---- inline pack: thread owns (row, word); 16 uint4 loads -> one uint64 ----
    {
        int row  = tid >> 4;
        int word = tid & (WORDS - 1);
        int gr   = r0 + row;
        unsigned long long m = 0ull;
        if (gr >= 0 && gr < HH) {
            const uint4* src = reinterpret_cast<const uint4*>(yt + (size_t)gr * WW + word * 64);
            #pragma unroll
            for (int i = 0; i < 16; ++i) {
                uint4 q = src[i];
                unsigned long long nib = (unsigned long long)(
                    (q.x ? 1u : 0u) | (q.y ? 2u : 0u) | (q.z ? 4u : 0u) | (q.w ? 8u : 0u));
                m |= nib << (4 * i);
            }
        }
        bits0[row][word] = m;
        bufA[row][word]  = m;
    }
    __syncthreads();

    // ---- 4 merged 3x3 erosions (h+v in one pass), ping-pong, shrinking halo ----
    #pragma unroll
    for (int k = 1; k <= 4; ++k) {
        unsigned long long (*src)[WPAD] = (k & 1) ? bufA : bufB;
        unsigned long long (*dst)[WPAD] = (k & 1) ? bufB : bufA;
        int lo = k, hi = ROWS - k;
        int n  = (hi - lo) * WORDS;          // <= 224 <= 256: one item/thread
        if (tid < n) {
            int row  = lo + (tid >> 4);
            int word = tid & (WORDS - 1);
            unsigned long long h0, h1, h2;
            {
                unsigned long long m = src[row - 1][word];
                unsigned long long l = (word > 0)         ? src[row - 1][word - 1] : 0ull;
                unsigned long long r = (word < WORDS - 1) ? src[row - 1][word + 1] : 0ull;
                h0 = m & ((m << 1) | (l >> 63)) & ((m >> 1) | (r << 63));
            }
            {
                unsigned long long m = src[row][word];
                unsigned long long l = (word > 0)         ? src[row][word - 1] : 0ull;
                unsigned long long r = (word < WORDS - 1) ? src[row][word + 1] : 0ull;
                h1 = m & ((m << 1) | (l >> 63)) & ((m >> 1) | (r << 63));
            }
            {
                unsigned long long m = src[row + 1][word];
                unsigned long long l = (word > 0)         ? src[row + 1][word - 1] : 0ull;
                unsigned long long r = (word < WORDS - 1) ? src[row + 1][word + 1] : 0ull;
                h2 = m & ((m << 1) | (l >> 63)) & ((m >> 1) | (r << 63));
            }
            unsigned long long res = h0 & h1 & h2;
            dst[row][word] = res;
            if (row >= HALO && row < HALO + TH) E[k - 1][row - HALO][word] = res;
        }
        __syncthreads();
    }

    // ---- emit 4-bit counts: thread t -> row=t>>5, groups 2*(t&31), +1 ----
    // group g = 16 pixels at col g*16; one uint64 of 16 nibble-counts.
    {
        int row = tid >> 5;            // 0..7
        int g0  = (tid & 31) * 2;      // even group index 0..62
        unsigned long long o0 = 0, o1 = 0;
        #pragma unroll
        for (int dg = 0; dg < 2; ++dg) {
            int g    = g0 + dg;
            int word = g >> 2;
            int sh   = (g & 3) * 16;
            unsigned int s0 = (unsigned int)((bits0[row + HALO][word] >> sh) & 0xFFFFull);
            unsigned int s1 = (unsigned int)((E[0][row][word]      >> sh) & 0xFFFFull);
            unsigned int s2 = (unsigned int)((E[1][row][word]      >> sh) & 0xFFFFull);
            unsigned int s3 = (unsigned int)((E[2][row][word]      >> sh) & 0xFFFFull);
            unsigned int s4 = (unsigned int)((E[3][row][word]      >> sh) & 0xFFFFull);
            unsigned long long c = spread16(s0) + spread16(s1) + spread16(s2)
                                 + spread16(s3) + spread16(s4);
            if (dg == 0) o0 = c; else o1 = c;
        }
        size_t base = ((size_t)im * HH + (size_t)(r0 + HALO + row)) * (WW / 16) + g0;
        ulonglong2 v; v.x = o0; v.y = o1;
        *reinterpret_cast<ulonglong2*>(&counts[base]) = v;   // 16 B store
    }
}

// ---------- kernel 2: pure streaming weighted MSE over count plane ----------
// thread: 1 float4 y_pred (coalesced 1 KB/wave) + 1 ushort (4 counts).
// block b covers groups [b*2048, b*2048+2048) -> 128 blocks per image.
__global__ __launch_bounds__(NTHREADS) void mse_kernel(
    const float* __restrict__ y_pred,
    const unsigned short* __restrict__ counts16,
    float* __restrict__ ws_partial)
{
    __shared__ float wavesum[NWAVES];
    const int tid  = threadIdx.x;
    const int lane = tid & 63;
    const int wave = tid >> 6;
    const size_t base = (size_t)blockIdx.x * 2048;   // float4-group index

    float lsum = 0.0f;
    #pragma unroll
    for (int it = 0; it < 8; ++it) {
        size_t idx = base + (size_t)it * NTHREADS + tid;
        float4 p = reinterpret_cast<const float4*>(y_pred)[idx];
        unsigned int cs = counts16[idx];
        float pvals[4] = {p.x, p.y, p.z, p.w};
        #pragma unroll
        for (int j = 0; j < 4; ++j) {
            unsigned int c = (cs >> (4 * j)) & 15u;
            float y = (c != 0u) ? 1.0f : 0.0f;
            float w = (c == 0u || c == 5u) ? 0.8f : (0.3f + 0.1f * (float)c);
            float d = pvals[j] - y;
            lsum += d * d * w;
        }
    }

    for (int off = 32; off > 0; off >>= 1)
        lsum += __shfl_down(lsum, off, 64);
    if (lane == 0) wavesum[wave] = lsum;
    __syncthreads();
    if (tid == 0) {
        float s = 0.0f;
        for (int wv = 0; wv < NWAVES; ++wv) s += wavesum[wv];
        ws_partial[blockIdx.x] = s;
    }
}

// ---------------- kernel 3: final reduction over 2048 block partials ----------
__global__ __launch_bounds__(NTHREADS) void reduce_kernel(
    const float* __restrict__ partial,
    float* __restrict__ out)
{
    __shared__ float ssum[NTHREADS];
    __shared__ float imsum[BATCH];
    const int tid = threadIdx.x;
    float s = 0.0f;
    #pragma unroll
    for (int j = 0; j < NBLOCKS_MSE / NTHREADS; ++j)
        s += partial[tid * (NBLOCKS_MSE / NTHREADS) + j];
    ssum[tid] = s;
    __syncthreads();
    if (tid < BATCH) {                      // 16 threads, one image each
        float a = 0.0f;
        #pragma unroll
        for (int t = 0; t < NTHREADS / BATCH; ++t)
            a += ssum[tid * (NTHREADS / BATCH) + t];
        imsum[tid] = a;
        out[tid] = a * (1.0f / (float)(HH * WW));
    }
    __syncthreads();
    if (tid == 0) {
        float tot = 0.0f;
        #pragma unroll
        for (int i = 0; i < BATCH; ++i) tot += imsum[i];
        out[BATCH] = tot * (1.0f / ((float)BATCH * (float)(HH * WW)));
    }
}

// ---------------- fallback: single-kernel path (atomics, needs memset) -------
__global__ __launch_bounds__(NTHREADS) void circle_mse_kernel(
    const float* __restrict__ y_pred,
    const float* __restrict__ y_true,
    float* __restrict__ out)
{
    __shared__ unsigned long long bits0[ROWS][WPAD];
    __shared__ unsigned long long cur[ROWS][WPAD];
    __shared__ unsigned long long tmp[ROWS][WPAD];
    __shared__ unsigned long long E[4][TH][WPAD];
    __shared__ float wavesum[NWAVES];

    const int tid  = threadIdx.x;
    const int lane = tid & 63;
    const int wave = tid >> 6;
    const int im = blockIdx.x / (HH / TH);
    const int rb = blockIdx.x % (HH / TH);
    const int r0 = rb * TH - HALO;
    const float* yt = y_true + (size_t)im * HH * WW;
    const float* yp = y_pred + (size_t)im * HH * WW;

    #pragma unroll 8
    for (int p = wave; p < ROWS * WORDS; p += NWAVES) {
        int row  = p >> 4;
        int word = p & (WORDS - 1);
        int gr   = r0 + row;
        unsigned long long m = 0ull;
        if (gr >= 0 && gr < HH) {
            float v = yt[(size_t)gr * WW + word * 64 + lane];
            m = __ballot(v != 0.0f);
        }
        if (lane == 0) { bits0[row][word] = m; cur[row][word] = m; }
    }
    __syncthreads();

    for (int k = 1; k <= 4; ++k) {
        int lo = k - 1, hi = ROWS - (k - 1);
        for (int p = tid; p < (hi - lo) * WORDS; p += NTHREADS) {
            int row  = lo + (p >> 4);
            int word = p & (WORDS - 1);
            unsigned long long m = cur[row][word];
            unsigned long long l = (word > 0)         ? cur[row][word - 1] : 0ull;
            unsigned long long r = (word < WORDS - 1) ? cur[row][word + 1] : 0ull;
            tmp[row][word] = m & ((m << 1) | (l >> 63)) & ((m >> 1) | (r << 63));
        }
        __syncthreads();
        lo = k; hi = ROWS - k;
        for (int p = tid; p < (hi - lo) * WORDS; p += NTHREADS) {
            int row  = lo + (p >> 4);
            int word = p & (WORDS - 1);
            unsigned long long res = tmp[row - 1][word] & tmp[row][word] & tmp[row + 1][word];
            cur[row][word] = res;
            if (row >= HALO && row < HALO + TH) E[k - 1][row - HALO][word] = res;
        }
        __syncthreads();
    }

    const int word = tid >> 4;
    const int bsh  = (tid & 15) * 4;
    float lsum = 0.0f;
    #pragma unroll
    for (int row = 0; row < TH; ++row) {
        int gr = r0 + HALO + row;
        float4 pv = *reinterpret_cast<const float4*>(&yp[(size_t)gr * WW + tid * 4]);
        unsigned int y4 = (unsigned int)((bits0[row + HALO][word] >> bsh) & 0xFull);
        unsigned int n1 = (unsigned int)((E[0][row][word] >> bsh) & 0xFull);
        unsigned int n2 = (unsigned int)((E[1][row][word] >> bsh) & 0xFull);
        unsigned int n3 = (unsigned int)((E[2][row][word] >> bsh) & 0xFull);
        unsigned int n4 = (unsigned int)((E[3][row][word] >> bsh) & 0xFull);
        float pvals[4] = {pv.x, pv.y, pv.z, pv.w};
        #pragma unroll
        for (int j = 0; j < 4; ++j) {
            unsigned int y = (y4 >> j) & 1u;
            unsigned int c = y + ((n1 >> j) & 1u) + ((n2 >> j) & 1u)
                               + ((n3 >> j) & 1u) + ((n4 >> j) & 1u);
            float w = (c == 0u || c == 5u) ? 0.8f : (0.3f + 0.1f * (float)c);
            float d = pvals[j] - (float)y;
            lsum += d * d * w;
        }
    }
    for (int off = 32; off > 0; off >>= 1)
        lsum += __shfl_down(lsum, off, 64);
    if (lane == 0) wavesum[wave] = lsum;
    __syncthreads();
    if (tid == 0) {
        float s = 0.0f;
        for (int wv = 0; wv < NWAVES; ++wv) s += wavesum[wv];
        atomicAdd(&out[im], s * (1.0f / (float)(HH * WW)));
        atomicAdd(&out[BATCH], s * (1.0f / ((float)BATCH * (float)(HH * WW))));
    }
}

extern "C" void kernel_launch(void* const* d_in, const int* in_sizes, int n_in,
                              void* d_out, int out_size, void* d_ws, size_t ws_size,
                              hipStream_t stream) {
    const float* y_pred = (const float*)d_in[0];
    const float* y_true = (const float*)d_in[1];
    float* out = (float*)d_out;

    const size_t need = (size_t)COUNT_WORDS * sizeof(unsigned long long)
                      + (size_t)NBLOCKS_MSE * sizeof(float);   // 8 MB + 8 KB
    if (ws_size >= need && d_ws != nullptr) {
        unsigned long long* counts = (unsigned long long*)d_ws;
        float* ws_partial = (float*)(counts + COUNT_WORDS);
        pack_erode_kernel<<<dim3(NBLOCKS_MSE), NTHREADS, 0, stream>>>(y_true, counts);
        mse_kernel<<<dim3(NBLOCKS_MSE), NTHREADS, 0, stream>>>(
            y_pred, (const unsigned short*)counts, ws_partial);
        reduce_kernel<<<dim3(1), NTHREADS, 0, stream>>>(ws_partial, out);
    } else {
        hipMemsetAsync(d_out, 0, (size_t)out_size * sizeof(float), stream);
        circle_mse_kernel<<<dim3(NBLOCKS_MSE), NTHREADS, 0, stream>>>(y_pred, y_true, out);
    }
}

// Round 11
// 159.614 us; speedup vs baseline: 1.0120x; 1.0120x over previous
//
#include <hip/hip_runtime.h>
#include <stdint.h>

#define BATCH 16
#define HH 1024
#define WW 1024
#define WORDS (WW/64)         // 16 uint64 words per row
#define NTHREADS 256
#define NWAVES (NTHREADS/64)
#define TOTAL_WORDS (BATCH * HH * WORDS)   // 262144 words = 2 MB packed
#define NBLOCKS_WIN (BATCH * HH)           // 16384: one image-row per block
#define PACK_BLOCKS (TOTAL_WORDS / 32 / NWAVES)  // 2048

typedef unsigned long long u64;

// ---------------- kernel 1: ballot-pack y_true into bit-plane ----------------
// 32 words per wave => 8192 waves => 32 waves/CU (100% occupancy). Measured good (r5).
__global__ __launch_bounds__(NTHREADS) void pack_kernel(
    const float* __restrict__ y_true,
    u64* __restrict__ packed)
{
    const int lane = threadIdx.x & 63;
    const size_t base = ((size_t)((blockIdx.x * NTHREADS + threadIdx.x) >> 6)) * 32;
    u64 mine = 0ull;
    #pragma unroll
    for (int i = 0; i < 32; ++i) {
        float v = y_true[(base + (size_t)i) * 64 + lane];
        u64 m = __ballot(v != 0.0f);
        mine = (lane == i) ? m : mine;
    }
    if (lane < 32) packed[base + lane] = mine;   // 256 B coalesced per wave
}

// -------- kernel 2: per-thread windowed erosion (registers) + fused MSE ------
// Thread t of block (im,row) owns 4 px at cols 4t..4t+3. Erosion-4 needs a
// 9-row x 12-col window = 9 uint32 registers. 4 shrink-window erosion steps,
// count c = y+e1+e2+e3+e4 per px (e4⊆e3⊆e2⊆e1⊆y), then weighted MSE.
// One tiny LDS stage (9 rows x 16 words = 1.2 KB) + ONE barrier. No ping-pong.
__global__ __launch_bounds__(NTHREADS) void erode_mse_win_kernel(
    const float* __restrict__ y_pred,
    const u64* __restrict__ packed,
    float* __restrict__ ws_partial)
{
    __shared__ u64 rows_s[9][WORDS];
    __shared__ float wavesum[NWAVES];

    const int tid = threadIdx.x;
    const int lane = tid & 63;
    const int wave = tid >> 6;
    const int b  = blockIdx.x;
    const int im = b >> 10;          // /HH
    const int r  = b & (HH - 1);

    // prefetch y_pred float4 (issued before the barrier; hides under erosion)
    const size_t pidx = ((size_t)im * HH + r) * (WW / 4) + tid;
    float4 p = reinterpret_cast<const float4*>(y_pred)[pidx];

    // stage 9 packed rows (r-4 .. r+4), zero outside image (= zero-pad erosion)
    if (tid < 9 * WORDS) {
        int d = tid >> 4, w = tid & (WORDS - 1);
        int rr = r - 4 + d;
        rows_s[d][w] = (rr >= 0 && rr < HH)
                     ? packed[((size_t)im * HH + rr) * WORDS + w] : 0ull;
    }
    __syncthreads();

    // build 12-bit windows: bit i = col (4*tid - 4 + i)
    const int w  = tid >> 4;
    const int sh = ((tid & 15) << 2) - 4;   // -4, 0, 4, ..., 56
    unsigned int win[9];
    #pragma unroll
    for (int d = 0; d < 9; ++d) {
        u64 C = rows_s[d][w];
        u64 L = (w > 0)         ? rows_s[d][w - 1] : 0ull;
        u64 R = (w < WORDS - 1) ? rows_s[d][w + 1] : 0ull;
        u64 t;
        if (sh >= 0) {
            t = C >> sh;
            if (sh > 52) t |= R << (64 - sh);   // only sh==56: R<<8
        } else {                                 // sh==-4 (left image edge)
            t = (C << 4) | (L >> 60);
        }
        win[d] = (unsigned int)t & 0xFFFu;
    }

    // counts: start with y (center row, bits 4..7)
    int c0 = (win[4] >> 4) & 1, c1 = (win[4] >> 5) & 1,
        c2 = (win[4] >> 6) & 1, c3 = (win[4] >> 7) & 1;

    unsigned int h[9];
    // step 1: h rows 0..8, v rows 1..7
    #pragma unroll
    for (int d = 0; d < 9; ++d) h[d] = win[d] & (win[d] << 1) & (win[d] >> 1);
    #pragma unroll
    for (int d = 1; d < 8; ++d) win[d] = h[d - 1] & h[d] & h[d + 1];
    c0 += (win[4] >> 4) & 1; c1 += (win[4] >> 5) & 1;
    c2 += (win[4] >> 6) & 1; c3 += (win[4] >> 7) & 1;
    // step 2: h rows 1..7, v rows 2..6
    #pragma unroll
    for (int d = 1; d < 8; ++d) h[d] = win[d] & (win[d] << 1) & (win[d] >> 1);
    #pragma unroll
    for (int d = 2; d < 7; ++d) win[d] = h[d - 1] & h[d] & h[d + 1];
    c0 += (win[4] >> 4) & 1; c1 += (win[4] >> 5) & 1;
    c2 += (win[4] >> 6) & 1; c3 += (win[4] >> 7) & 1;
    // step 3: h rows 2..6, v rows 3..5
    #pragma unroll
    for (int d = 2; d < 7; ++d) h[d] = win[d] & (win[d] << 1) & (win[d] >> 1);
    #pragma unroll
    for (int d = 3; d < 6; ++d) win[d] = h[d - 1] & h[d] & h[d + 1];
    c0 += (win[4] >> 4) & 1; c1 += (win[4] >> 5) & 1;
    c2 += (win[4] >> 6) & 1; c3 += (win[4] >> 7) & 1;
    // step 4: h rows 3..5, v row 4
    #pragma unroll
    for (int d = 3; d < 6; ++d) h[d] = win[d] & (win[d] << 1) & (win[d] >> 1);
    win[4] = h[3] & h[4] & h[5];
    c0 += (win[4] >> 4) & 1; c1 += (win[4] >> 5) & 1;
    c2 += (win[4] >> 6) & 1; c3 += (win[4] >> 7) & 1;

    // weighted MSE for the 4 px (y = c>0; w = (c==0||c==5)?0.8:0.3+0.1c)
    float pv[4] = {p.x, p.y, p.z, p.w};
    int   cc[4] = {c0, c1, c2, c3};
    float lsum = 0.0f;
    #pragma unroll
    for (int j = 0; j < 4; ++j) {
        int   c = cc[j];
        float y = (c != 0) ? 1.0f : 0.0f;
        float wt = (c == 0 || c == 5) ? 0.8f : (0.3f + 0.1f * (float)c);
        float d = pv[j] - y;
        lsum += d * d * wt;
    }

    // wave + block reduce -> one partial per block (no atomics)
    for (int off = 32; off > 0; off >>= 1)
        lsum += __shfl_down(lsum, off, 64);
    if (lane == 0) wavesum[wave] = lsum;
    __syncthreads();
    if (tid == 0) {
        float s = 0.0f;
        for (int wv = 0; wv < NWAVES; ++wv) s += wavesum[wv];
        ws_partial[b] = s;
    }
}

// ------------- kernel 3: final reduction over 16384 row partials -------------
// partial[b], b = im*1024 + r. thread t: image t/16, 64 consecutive rows.
__global__ __launch_bounds__(NTHREADS) void reduce_kernel(
    const float* __restrict__ partial,
    float* __restrict__ out)
{
    __shared__ float ssum[NTHREADS];
    __shared__ float imsum[BATCH];
    const int tid = threadIdx.x;
    const int im    = tid >> 4;        // 16 threads per image
    const int chunk = tid & 15;
    size_t base = (size_t)im * (HH) + (size_t)chunk * 64;
    float s = 0.0f;
    #pragma unroll 8
    for (int j = 0; j < 64; ++j) s += partial[base + j];
    ssum[tid] = s;
    __syncthreads();
    if (tid < BATCH) {
        float a = 0.0f;
        #pragma unroll
        for (int t = 0; t < 16; ++t) a += ssum[tid * 16 + t];
        imsum[tid] = a;
        out[tid] = a * (1.0f / (float)(HH * WW));
    }
    __syncthreads();
    if (tid == 0) {
        float tot = 0.0f;
        #pragma unroll
        for (int i = 0; i < BATCH; ++i) tot += imsum[i];
        out[BATCH] = tot * (1.0f / ((float)BATCH * (float)(HH * WW)));
    }
}

// ---------------- fallback: single-kernel path (atomics, needs memset) -------
#define TH 8
#define HALO 4
#define ROWS (TH + 2*HALO)
#define WPAD (WORDS + 1)
__global__ __launch_bounds__(NTHREADS) void circle_mse_kernel(
    const float* __restrict__ y_pred,
    const float* __restrict__ y_true,
    float* __restrict__ out)
{
    __shared__ u64 bits0[ROWS][WPAD];
    __shared__ u64 cur[ROWS][WPAD];
    __shared__ u64 tmp[ROWS][WPAD];
    __shared__ u64 E[4][TH][WPAD];
    __shared__ float wavesum[NWAVES];

    const int tid  = threadIdx.x;
    const int lane = tid & 63;
    const int wave = tid >> 6;
    const int im = blockIdx.x / (HH / TH);
    const int rb = blockIdx.x % (HH / TH);
    const int r0 = rb * TH - HALO;
    const float* yt = y_true + (size_t)im * HH * WW;
    const float* yp = y_pred + (size_t)im * HH * WW;

    #pragma unroll 8
    for (int p = wave; p < ROWS * WORDS; p += NWAVES) {
        int row  = p >> 4;
        int word = p & (WORDS - 1);
        int gr   = r0 + row;
        u64 m = 0ull;
        if (gr >= 0 && gr < HH) {
            float v = yt[(size_t)gr * WW + word * 64 + lane];
            m = __ballot(v != 0.0f);
        }
        if (lane == 0) { bits0[row][word] = m; cur[row][word] = m; }
    }
    __syncthreads();

    for (int k = 1; k <= 4; ++k) {
        int lo = k - 1, hi = ROWS - (k - 1);
        for (int p = tid; p < (hi - lo) * WORDS; p += NTHREADS) {
            int row  = lo + (p >> 4);
            int word = p & (WORDS - 1);
            u64 m = cur[row][word];
            u64 l = (word > 0)         ? cur[row][word - 1] : 0ull;
            u64 r = (word < WORDS - 1) ? cur[row][word + 1] : 0ull;
            tmp[row][word] = m & ((m << 1) | (l >> 63)) & ((m >> 1) | (r << 63));
        }
        __syncthreads();
        lo = k; hi = ROWS - k;
        for (int p = tid; p < (hi - lo) * WORDS; p += NTHREADS) {
            int row  = lo + (p >> 4);
            int word = p & (WORDS - 1);
            u64 res = tmp[row - 1][word] & tmp[row][word] & tmp[row + 1][word];
            cur[row][word] = res;
            if (row >= HALO && row < HALO + TH) E[k - 1][row - HALO][word] = res;
        }
        __syncthreads();
    }

    const int word = tid >> 4;
    const int bsh  = (tid & 15) * 4;
    float lsum = 0.0f;
    #pragma unroll
    for (int row = 0; row < TH; ++row) {
        int gr = r0 + HALO + row;
        float4 pv = *reinterpret_cast<const float4*>(&yp[(size_t)gr * WW + tid * 4]);
        unsigned int y4 = (unsigned int)((bits0[row + HALO][word] >> bsh) & 0xFull);
        unsigned int n1 = (unsigned int)((E[0][row][word] >> bsh) & 0xFull);
        unsigned int n2 = (unsigned int)((E[1][row][word] >> bsh) & 0xFull);
        unsigned int n3 = (unsigned int)((E[2][row][word] >> bsh) & 0xFull);
        unsigned int n4 = (unsigned int)((E[3][row][word] >> bsh) & 0xFull);
        float pvals[4] = {pv.x, pv.y, pv.z, pv.w};
        #pragma unroll
        for (int j = 0; j < 4; ++j) {
            unsigned int y = (y4 >> j) & 1u;
            unsigned int c = y + ((n1 >> j) & 1u) + ((n2 >> j) & 1u)
                               + ((n3 >> j) & 1u) + ((n4 >> j) & 1u);
            float w = (c == 0u || c == 5u) ? 0.8f : (0.3f + 0.1f * (float)c);
            float d = pvals[j] - (float)y;
            lsum += d * d * w;
        }
    }
    for (int off = 32; off > 0; off >>= 1)
        lsum += __shfl_down(lsum, off, 64);
    if (lane == 0) wavesum[wave] = lsum;
    __syncthreads();
    if (tid == 0) {
        float s = 0.0f;
        for (int wv = 0; wv < NWAVES; ++wv) s += wavesum[wv];
        atomicAdd(&out[im], s * (1.0f / (float)(HH * WW)));
        atomicAdd(&out[BATCH], s * (1.0f / ((float)BATCH * (float)(HH * WW))));
    }
}

extern "C" void kernel_launch(void* const* d_in, const int* in_sizes, int n_in,
                              void* d_out, int out_size, void* d_ws, size_t ws_size,
                              hipStream_t stream) {
    const float* y_pred = (const float*)d_in[0];
    const float* y_true = (const float*)d_in[1];
    float* out = (float*)d_out;

    const size_t need = (size_t)TOTAL_WORDS * sizeof(u64)
                      + (size_t)NBLOCKS_WIN * sizeof(float);   // 2 MB + 64 KB
    if (ws_size >= need && d_ws != nullptr) {
        u64* packed = (u64*)d_ws;
        float* ws_partial = (float*)(packed + TOTAL_WORDS);
        pack_kernel<<<dim3(PACK_BLOCKS), NTHREADS, 0, stream>>>(y_true, packed);
        erode_mse_win_kernel<<<dim3(NBLOCKS_WIN), NTHREADS, 0, stream>>>(
            y_pred, packed, ws_partial);
        reduce_kernel<<<dim3(1), NTHREADS, 0, stream>>>(ws_partial, out);
    } else {
        hipMemsetAsync(d_out, 0, (size_t)out_size * sizeof(float), stream);
        circle_mse_kernel<<<dim3(BATCH * (HH / TH)), NTHREADS, 0, stream>>>(y_pred, y_true, out);
    }
}